// Round 1
// baseline (299.458 us; speedup 1.0000x reference)
//
#include <hip/hip_runtime.h>
#include <hip/hip_bf16.h>
#include <cstdio>

typedef __bf16  bf16x8 __attribute__((ext_vector_type(8)));
typedef float   f32x4  __attribute__((ext_vector_type(4)));
typedef unsigned short u16;
typedef u16     u16x8  __attribute__((ext_vector_type(8)));

// ---------- helpers ----------

__device__ __forceinline__ void gld_lds16(const void* g, void* l) {
  // async global->LDS, 16B per lane; LDS dest is wave-uniform base + lane*16
  __builtin_amdgcn_global_load_lds(
      (const __attribute__((address_space(1))) unsigned int*)g,
      (__attribute__((address_space(3))) unsigned int*)l,
      16, 0, 0);
}

__device__ __forceinline__ u16 f2bf(float f) {
  union { float f; unsigned int u; } c{f};
  unsigned int u = c.u;
  u += 0x7fffu + ((u >> 16) & 1u);   // round-to-nearest-even
  return (u16)(u >> 16);
}

__device__ __forceinline__ float bf2f(u16 h) {
  union { unsigned int u; float f; } c{(unsigned int)h << 16};
  return c.f;
}

// ---------- elementwise / transpose kernels ----------

// x fp32 [8388608] -> bf16
__global__ __launch_bounds__(256) void cast_x_kernel(const float* __restrict__ x,
                                                     u16* __restrict__ o) {
  const int i = (blockIdx.x * 256 + threadIdx.x) * 8;
  float4 a = *(const float4*)(x + i);
  float4 b = *(const float4*)(x + i + 4);
  u16x8 r;
  r[0] = f2bf(a.x); r[1] = f2bf(a.y); r[2] = f2bf(a.z); r[3] = f2bf(a.w);
  r[4] = f2bf(b.x); r[5] = f2bf(b.y); r[6] = f2bf(b.z); r[7] = f2bf(b.w);
  *(u16x8*)(o + i) = r;
}

// kernel fp32 [4][1024][1024] slices 0..2 -> WT bf16 [3][1024e][1024d]  (WT[s][e][d] = k[s][d][e])
__global__ void pack_w_kernel(const float* __restrict__ w, u16* __restrict__ wt) {
  __shared__ float tile[32][33];
  const int s = blockIdx.z, e0 = blockIdx.x * 32, d0 = blockIdx.y * 32;
  const int tx = threadIdx.x, ty = threadIdx.y;
  const float* in = w + (size_t)s * 1048576;
#pragma unroll
  for (int j = 0; j < 4; ++j)
    tile[ty + j * 8][tx] = in[(size_t)(d0 + ty + j * 8) * 1024 + e0 + tx];
  __syncthreads();
  u16* o = wt + (size_t)s * 1048576;
#pragma unroll
  for (int j = 0; j < 4; ++j)
    o[(size_t)(e0 + ty + j * 8) * 1024 + d0 + tx] = f2bf(tile[tx][ty + j * 8]);
}

// WQKV bf16 [8192][3072], V slice cols 2048..3071 -> VT bf16 [4][1024e][2048k]
__global__ void transpose_v_kernel(const u16* __restrict__ wqkv, u16* __restrict__ vt) {
  __shared__ u16 tile[32][33];
  const int b = blockIdx.z, e0 = blockIdx.x * 32, k0 = blockIdx.y * 32;
  const int tx = threadIdx.x, ty = threadIdx.y;
  const u16* in = wqkv + (size_t)b * 2048 * 3072 + 2048;
#pragma unroll
  for (int j = 0; j < 4; ++j)
    tile[ty + j * 8][tx] = in[(size_t)(k0 + ty + j * 8) * 3072 + e0 + tx];
  __syncthreads();
  u16* o = vt + (size_t)b * 1024 * 2048;
#pragma unroll
  for (int j = 0; j < 4; ++j)
    o[(size_t)(e0 + ty + j * 8) * 2048 + k0 + tx] = tile[tx][ty + j * 8];
}

// in-place row softmax on bf16 scores [8192 rows][2048], logits = s * (1/32)
__global__ __launch_bounds__(256) void softmax_kernel(u16* __restrict__ SP) {
  u16* p = SP + (size_t)blockIdx.x * 2048;
  const int t = threadIdx.x;
  const int w = t >> 6, l = t & 63;
  u16x8 v = *(const u16x8*)(p + t * 8);
  float f[8];
#pragma unroll
  for (int i = 0; i < 8; ++i) f[i] = bf2f(v[i]);
  float m = f[0];
#pragma unroll
  for (int i = 1; i < 8; ++i) m = fmaxf(m, f[i]);
#pragma unroll
  for (int o = 32; o >= 1; o >>= 1) m = fmaxf(m, __shfl_xor(m, o, 64));
  __shared__ float red[8];
  if (l == 0) red[w] = m;
  __syncthreads();
  m = fmaxf(fmaxf(red[0], red[1]), fmaxf(red[2], red[3]));
  float e[8], s = 0.f;
#pragma unroll
  for (int i = 0; i < 8; ++i) { e[i] = __expf((f[i] - m) * 0.03125f); s += e[i]; }
#pragma unroll
  for (int o = 32; o >= 1; o >>= 1) s += __shfl_xor(s, o, 64);
  if (l == 0) red[4 + w] = s;
  __syncthreads();
  s = red[4] + red[5] + red[6] + red[7];
  const float inv = 1.0f / s;
  u16x8 r;
#pragma unroll
  for (int i = 0; i < 8; ++i) r[i] = f2bf(e[i] * inv);
  *(u16x8*)(p + t * 8) = r;
}

// ---------- BT-GEMM: C[M,N] = A[M,K] * B[N,K]^T, bf16 in, fp32 acc ----------
// grid: (N/128, M/128, batch); block 256 (4 waves, 2x2 of 64x64)

template <bool OUT_BF16>
__global__ __launch_bounds__(256)
void gemm_bt(const u16* __restrict__ A, const u16* __restrict__ B,
             void* __restrict__ Cv, int K, int lda, int ldb, int ldc,
             long sA, long sB, long sC) {
  __shared__ __align__(16) u16 As[128 * 32];
  __shared__ __align__(16) u16 Bs[128 * 32];
  const int t = threadIdx.x;
  const int w = t >> 6, l = t & 63;
  const int bz = blockIdx.z;
  const u16* Ab = A + (long)bz * sA;
  const u16* Bb = B + (long)bz * sB;
  const int m0 = blockIdx.y * 128, n0 = blockIdx.x * 128;
  const int wm = w & 1, wn = w >> 1;
  const int lr = l & 15, lq = l >> 4;
  const int srow = l >> 2;        // staging: row within 16-row chunk
  const int scol = (l & 3) * 8;   // staging: bf16 col offset (16B per lane)

  f32x4 acc[4][4] = {};

  for (int k0 = 0; k0 < K; k0 += 32) {
    __syncthreads();
#pragma unroll
    for (int c = 0; c < 2; ++c) {
      const int rb = (w * 2 + c) * 16;  // 4 waves x 2 calls x 16 rows = 128
      gld_lds16(Ab + (long)(m0 + rb + srow) * lda + k0 + scol, (void*)(As + rb * 32));
      gld_lds16(Bb + (long)(n0 + rb + srow) * ldb + k0 + scol, (void*)(Bs + rb * 32));
    }
    __syncthreads();
    bf16x8 af[4], bfr[4];
#pragma unroll
    for (int i = 0; i < 4; ++i) {
      af[i]  = *(const bf16x8*)(As + (wm * 64 + i * 16 + lr) * 32 + lq * 8);
      bfr[i] = *(const bf16x8*)(Bs + (wn * 64 + i * 16 + lr) * 32 + lq * 8);
    }
#pragma unroll
    for (int mi = 0; mi < 4; ++mi)
#pragma unroll
      for (int ni = 0; ni < 4; ++ni)
        acc[mi][ni] = __builtin_amdgcn_mfma_f32_16x16x32_bf16(af[mi], bfr[ni], acc[mi][ni], 0, 0, 0);
  }

#pragma unroll
  for (int mi = 0; mi < 4; ++mi) {
#pragma unroll
    for (int i = 0; i < 4; ++i) {
      const int row = m0 + wm * 64 + mi * 16 + lq * 4 + i;
#pragma unroll
      for (int ni = 0; ni < 4; ++ni) {
        const int col = n0 + wn * 64 + ni * 16 + lr;
        const float val = acc[mi][ni][i];
        if (OUT_BF16)
          ((u16*)Cv)[(long)bz * sC + (long)row * ldc + col] = f2bf(val);
        else
          ((float*)Cv)[(long)bz * sC + (long)row * ldc + col] = val;
      }
    }
  }
}

// ---------- launch ----------

extern "C" void kernel_launch(void* const* d_in, const int* in_sizes, int n_in,
                              void* d_out, int out_size, void* d_ws, size_t ws_size,
                              hipStream_t stream) {
  (void)in_sizes; (void)n_in; (void)out_size;
  const float* x    = (const float*)d_in[0];
  const float* kern = (const float*)d_in[1];
  float* out = (float*)d_out;
  char* ws = (char*)d_ws;
  const size_t MB = 1024 * 1024;
  u16* xbf  = (u16*)(ws);             // 16 MB: [8192][1024] bf16
  u16* WT   = (u16*)(ws + 16 * MB);   //  6 MB: [3][1024][1024] bf16 (transposed weights)
  u16* WQKV = (u16*)(ws + 22 * MB);   // 48 MB: [8192][3072] bf16 (Q|K|V)
  u16* VT   = (u16*)(ws + 70 * MB);   // 16 MB: [4][1024][2048] bf16
  u16* SP   = (u16*)(ws + 86 * MB);   // 32 MB: [4][2048][2048] bf16 scores->probs
  if (ws_size < 118 * MB)
    fprintf(stderr, "WARNING: ws_size %zu < needed %zu\n", ws_size, (size_t)(118 * MB));

  cast_x_kernel<<<4096, 256, 0, stream>>>(x, xbf);
  pack_w_kernel<<<dim3(32, 32, 3), dim3(32, 8), 0, stream>>>(kern, WT);
  // WQKV[m, s*1024+e] = xbf[m,:] . WT[s*1024+e,:]
  gemm_bt<true><<<dim3(24, 64, 1), 256, 0, stream>>>(
      xbf, WT, WQKV, 1024, 1024, 1024, 3072, 0, 0, 0);
  // S[b][q][k] = Q[b][q,:] . K[b][k,:]
  gemm_bt<true><<<dim3(16, 16, 4), 256, 0, stream>>>(
      WQKV, WQKV + 1024, SP, 1024, 3072, 3072, 2048,
      2048L * 3072, 2048L * 3072, 2048L * 2048);
  transpose_v_kernel<<<dim3(32, 64, 4), dim3(32, 8), 0, stream>>>(WQKV, VT);
  softmax_kernel<<<8192, 256, 0, stream>>>(SP);
  // out[b][q][e] = P[b][q,:] . VT[b][e,:]
  gemm_bt<false><<<dim3(8, 16, 4), 256, 0, stream>>>(
      SP, VT, out, 2048, 2048, 2048, 1024,
      2048L * 2048, 1024L * 2048, 2048L * 1024);
}